// Round 1
// 424.531 us; speedup vs baseline: 1.0636x; 1.0636x over previous
//
#include <hip/hip_runtime.h>

#define EPS 1e-9f

constexpr int B_ = 8, N_ = 2048, M_ = 2048;
constexpr int THREADS = 512;                 // 8 waves/block (was 256/4):
constexpr int WAVES = 8;                     //   2 blocks/CU * 8 waves = 16 waves/CU
constexpr int RPW = 4;                       // rows per wave (was 8)
constexpr int RPB = WAVES * RPW;             // 32 rows per block (unchanged)
constexpr int BPB = N_ / RPB;                // 64 blocks per batch
constexpr int GRID = B_ * BPB;               // 512 blocks = 2/CU exactly

__global__ __launch_bounds__(256) void init_kernel(float* rL, float* fb,
                                                   float* ss0, float* out) {
    int i = blockIdx.x * blockDim.x + threadIdx.x;
    if (i < B_ * N_) { rL[i] = 1.f; fb[i] = 0.f; ss0[i] = 0.f; }
    if (i < B_) out[i] = 0.f;
}

// One kernel per annealing step s: [phase2 of step s-1] fused with [phase1 of
// step s]. NEW in this version: phase2 and phase1-rowsum sweep the SAME d2
// values, so they share a single k-loop (one d2 computation instead of two),
// and xyz is staged once (float4 x,y,z,rn + separate g array, 40 KB live).
// The 8-wave column-sum reduction overlays the full 64 KB LDS after a barrier
// (deterministic fixed-order sum, same as the old 4-wave ssl scheme).
__global__ __launch_bounds__(THREADS, 4) void fused_step(
        const float* __restrict__ xyz1, const float* __restrict__ xyz2,
        float* __restrict__ rLb, float* __restrict__ fb,
        const float* __restrict__ rRp,   // rR(s-1) in   (unused if !has_p2)
        float* __restrict__ rRn_g,       // rR(s)  out   (designated block)
        const float* __restrict__ ssp_g, // ss(s-1) in   (unused if !has_p2)
        float* __restrict__ ssc_g,       // ss(s) atomic accumulate (pre-zeroed)
        float* __restrict__ ssz_g,       // ss(s+1) zeroed here for next kernel
        float* __restrict__ out,
        float l2p, float l2c, int has_p2, int has_p1)
{
    // raw[0:8192)        : sp  = float4 (x,y,z,rn)      32 KB
    // raw[8192:10240)    : sg  = g                       8 KB
    // raw[0:16384)       : ssl overlay (8 waves x 2048) 64 KB, after passB sync
    // raw[16384:16392)   : wcost
    __shared__ __align__(16) float raw[8 * M_ + WAVES];
    float4* sp    = (float4*)raw;
    float*  sg    = raw + 4 * M_;
    float*  ssl   = raw;
    float*  wcost = raw + 8 * M_;

    const int b   = blockIdx.x / BPB;
    const int blk = blockIdx.x % BPB;
    const int n0  = blk * RPB;
    const int tid = threadIdx.x;
    const bool designated = (blk == 0);

    // ---- staging: points + per-column factors for BOTH fused parts ----
    const float* x2 = xyz2 + (size_t)b * M_ * 3;
    for (int m = tid; m < M_; m += THREADS) {
        const float x = x2[3*m], y = x2[3*m+1], z = x2[3*m+2];
        float g = 0.f, rn = 1.f;
        if (has_p2) {
            const float rr = rRp[b * M_ + m];
            const float s  = ssp_g[b * M_ + m];
            const float ratio = fminf(rr / (s + EPS), 1.f);
            g  = rr * ratio;
            rn = fmaxf(rr - s * ratio, 0.f);
        }
        sp[m] = make_float4(x, y, z, rn);
        sg[m] = g;
        if (designated) {
            if (has_p1) rRn_g[b * M_ + m] = rn;
            ssz_g[b * M_ + m] = 0.f;
        }
    }
    __syncthreads();

    const int wave = tid >> 6, lane = tid & 63;
    const int nw = n0 + wave * RPW;

    float xv[RPW], yv[RPW], zv[RPW];
    #pragma unroll
    for (int r = 0; r < RPW; ++r) {
        const float* q = xyz1 + (size_t)(b * N_ + nw + r) * 3;
        xv[r] = q[0]; yv[r] = q[1]; zv[r] = q[2];
    }

    float accd[RPW], accc[RPW], p[RPW];
    #pragma unroll
    for (int r = 0; r < RPW; ++r) { accd[r] = 0.f; accc[r] = 0.f; p[r] = 0.f; }

    // ---- fused sweep: phase2(s-1) cost/rowsum + phase1(s) rowsum ----
    // (s=0 runs the merged loop with g==0, l2p==0 -> accd/accc exactly 0)
    if (has_p1) {
        #pragma unroll
        for (int k = 0; k < 32; ++k) {
            const float4 c = sp[lane + (k << 6)];
            const float  g = sg[lane + (k << 6)];
            #pragma unroll
            for (int r = 0; r < RPW; ++r) {
                const float dx = xv[r]-c.x, dy = yv[r]-c.y, dz = zv[r]-c.z;
                const float d2 = dx*dx + dy*dy + dz*dz;
                const float e = __builtin_amdgcn_exp2f(l2p * d2) * g;
                accd[r] += e;
                accc[r] += e * __builtin_amdgcn_sqrtf(fmaxf(d2, 1e-20f));
                p[r] += __builtin_amdgcn_exp2f(l2c * d2) * c.w;
            }
        }
    } else {
        // s=10: phase2-only
        #pragma unroll
        for (int k = 0; k < 32; ++k) {
            const float4 c = sp[lane + (k << 6)];
            const float  g = sg[lane + (k << 6)];
            #pragma unroll
            for (int r = 0; r < RPW; ++r) {
                const float dx = xv[r]-c.x, dy = yv[r]-c.y, dz = zv[r]-c.z;
                const float d2 = dx*dx + dy*dy + dz*dz;
                const float e = __builtin_amdgcn_exp2f(l2p * d2) * g;
                accd[r] += e;
                accc[r] += e * __builtin_amdgcn_sqrtf(fmaxf(d2, 1e-20f));
            }
        }
    }

    // ---- wave reductions (rows are wave-private) ----
    if (has_p2) {
        #pragma unroll
        for (int r = 0; r < RPW; ++r) {
            #pragma unroll
            for (int off = 32; off >= 1; off >>= 1) {
                accd[r] += __shfl_xor(accd[r], off, 64);
                accc[r] += __shfl_xor(accc[r], off, 64);
            }
        }
    }
    if (has_p1) {
        #pragma unroll
        for (int r = 0; r < RPW; ++r) {
            #pragma unroll
            for (int off = 32; off >= 1; off >>= 1)
                p[r] += __shfl_xor(p[r], off, 64);
        }
    }

    float rl_new[RPW];
    float cw = 0.f;
    if (has_p2) {
        #pragma unroll
        for (int r = 0; r < RPW; ++r) {
            const int idx = b * N_ + nw + r;
            const float fo = fb[idx];               // f(s-1), broadcast load
            const float rl = rLb[idx];
            rl_new[r] = fmaxf(rl - fo * accd[r], 0.f);
            cw += fo * accc[r];
        }
    } else {
        #pragma unroll
        for (int r = 0; r < RPW; ++r) rl_new[r] = 1.f;
    }
    if (lane == 0) wcost[wave] = cw;
    __syncthreads();
    if (tid == 0 && has_p2) {
        float t = 0.f;
        #pragma unroll
        for (int w = 0; w < WAVES; ++w) t += wcost[w];
        atomicAdd(&out[b], t);
    }

    // ---- phase1 colsums: f, ss accumulate ----
    if (has_p1) {
        float fn[RPW];
        #pragma unroll
        for (int r = 0; r < RPW; ++r)
            fn[r] = rl_new[r] / (p[r] + EPS);
        if (lane == 0) {
            #pragma unroll
            for (int r = 0; r < RPW; ++r) {
                const int idx = b * N_ + nw + r;
                fb[idx]  = fn[r];
                rLb[idx] = rl_new[r];
            }
        }
        // per-lane column partials (recompute e; no per-element storage)
        float ssp[32];
        #pragma unroll
        for (int k = 0; k < 32; ++k) {
            const float4 c = sp[lane + (k << 6)];
            float s = 0.f;
            #pragma unroll
            for (int r = 0; r < RPW; ++r) {
                const float dx = xv[r]-c.x, dy = yv[r]-c.y, dz = zv[r]-c.z;
                const float d2 = dx*dx + dy*dy + dz*dz;
                s += __builtin_amdgcn_exp2f(l2c * d2) * fn[r];
            }
            ssp[k] = s * c.w;
        }
        __syncthreads();   // all sp/sg reads done -> ssl overlay safe
        #pragma unroll
        for (int k = 0; k < 32; ++k)
            ssl[wave * M_ + lane + (k << 6)] = ssp[k];
        __syncthreads();
        for (int m = tid; m < M_; m += THREADS) {
            float s = ssl[m]          + ssl[M_ + m]     + ssl[2*M_ + m]
                    + ssl[3*M_ + m]   + ssl[4*M_ + m]   + ssl[5*M_ + m]
                    + ssl[6*M_ + m]   + ssl[7*M_ + m];
            atomicAdd(&ssc_g[b * M_ + m], s);
        }
    }
}

extern "C" void kernel_launch(void* const* d_in, const int* in_sizes, int n_in,
                              void* d_out, int out_size, void* d_ws, size_t ws_size,
                              hipStream_t stream) {
    const float* xyz1 = (const float*)d_in[0];
    const float* xyz2 = (const float*)d_in[1];
    float* out = (float*)d_out;
    float* ws = (float*)d_ws;
    const int SZ = B_ * N_;          // == B_*M_ == 16384
    float* rL  = ws;
    float* fb  = ws + SZ;
    float* rRb[2] = { ws + 2*SZ, ws + 3*SZ };
    float* ssb[3] = { ws + 4*SZ, ws + 5*SZ, ws + 6*SZ };

    init_kernel<<<(SZ + 255) / 256, 256, 0, stream>>>(rL, fb, ssb[0], out);

    constexpr float LOG2E = 1.4426950408889634f;
    static const float levels[10] = {
        -16384.f, -4096.f, -1024.f, -256.f, -64.f,
        -16.f, -4.f, -1.f, -0.25f, 0.f
    };
    // kernel s (s=0..10): phase2 of step s-1 (if s>0) + phase1 of step s (if s<10)
    for (int s = 0; s <= 10; ++s) {
        const int has_p2 = (s > 0);
        const int has_p1 = (s < 10);
        const float l2p = has_p2 ? levels[s-1] * LOG2E : 0.f;
        const float l2c = has_p1 ? levels[s]   * LOG2E : 0.f;
        fused_step<<<GRID, THREADS, 0, stream>>>(
            xyz1, xyz2, rL, fb,
            rRb[(s + 1) & 1],      // rR(s-1)   (s>=1; unused at s=0)
            rRb[s & 1],            // rR(s) out
            ssb[(s + 2) % 3],      // ss(s-1)   (s>=1; unused at s=0)
            ssb[s % 3],            // ss(s) accumulate (pre-zeroed by kernel s-1 / init)
            ssb[(s + 1) % 3],      // ss(s+1) zeroed for next kernel
            out, l2p, l2c, has_p2, has_p1);
    }
}